// Round 16
// baseline (90.444 us; speedup 1.0000x reference)
//
#include <hip/hip_runtime.h>

// h[v] = sum_{(u,v) in E} feat[u], feat: [N=100000,64] f32, E=1.2M.
// Round 16: gather via __builtin_amdgcn_global_load_lds (width 16).
// r9/r15 lesson: hipcc re-serializes VGPR-held gather loads (schedules for
// min registers; VGPR=56 despite launch_bounds(512,2)). global_load_lds is
// fire-and-forget with NO dest VGPRs: one instr = 4 scattered rows in
// flight. Reduce phase reads staged rows from LDS, lane = column (no shfl,
// coalesced stores). r14 decomposition: skeleton ~20us + random service
// ~23us -> both attacked (static 16-edge inner loop, batch-level MLP).

#define NBKT_BITS 7
#define NODES_PER_BKT 128      // 1 << NBKT_BITS
#define NBKT_CAP 1024
#define BIN_CHUNK 4096
#define SRC_MASK 0x1FFFF       // 17 bits, N=100000 < 131072
#define EDGE_CAP 2048          // per-bucket capacity; mean 1534, 13-sigma margin
#define NPW 16                 // nodes per wave (128 / 8 waves)
#define BATCH 16               // edges staged per wave per round

typedef __attribute__((address_space(1))) const unsigned int* gas_ptr;
typedef __attribute__((address_space(3))) unsigned int* las_ptr;

// ---------- LDS-aggregated direct-slot bin (int4 reads) ----------
__global__ __launch_bounds__(1024) void bin_direct_kernel(
        const int* __restrict__ src, const int* __restrict__ dst,
        int* __restrict__ bcnt, int* __restrict__ binned, int E, int NB) {
    __shared__ int cnt[NBKT_CAP];
    __shared__ int base[NBKT_CAP];
    const int beg = blockIdx.x * BIN_CHUNK;
    const int end = min(E, beg + BIN_CHUNK);
    const int nE = end - beg;
    for (int i = threadIdx.x; i < NB; i += blockDim.x) cnt[i] = 0;
    __syncthreads();
    if ((nE & 3) == 0) {
        const int nv = nE >> 2;
        for (int i = threadIdx.x; i < nv; i += blockDim.x) {
            const int4 d4 = *reinterpret_cast<const int4*>(dst + beg + i * 4);
            atomicAdd(&cnt[d4.x >> NBKT_BITS], 1);
            atomicAdd(&cnt[d4.y >> NBKT_BITS], 1);
            atomicAdd(&cnt[d4.z >> NBKT_BITS], 1);
            atomicAdd(&cnt[d4.w >> NBKT_BITS], 1);
        }
    } else {
        for (int i = beg + threadIdx.x; i < end; i += blockDim.x)
            atomicAdd(&cnt[dst[i] >> NBKT_BITS], 1);
    }
    __syncthreads();
    for (int i = threadIdx.x; i < NB; i += blockDim.x) {
        const int c = cnt[i];
        base[i] = c ? atomicAdd(&bcnt[i], c) : 0;
        cnt[i] = 0;
    }
    __syncthreads();
    if ((nE & 3) == 0) {
        const int nv = nE >> 2;
        for (int i = threadIdx.x; i < nv; i += blockDim.x) {
            const int4 d4 = *reinterpret_cast<const int4*>(dst + beg + i * 4);
            const int4 s4 = *reinterpret_cast<const int4*>(src + beg + i * 4);
            {
                const int b = d4.x >> NBKT_BITS;
                const int r = atomicAdd(&cnt[b], 1);
                const int pos = base[b] + r;
                if (pos < EDGE_CAP)
                    binned[(size_t)b * EDGE_CAP + pos] = s4.x | ((d4.x & (NODES_PER_BKT - 1)) << 17);
            }
            {
                const int b = d4.y >> NBKT_BITS;
                const int r = atomicAdd(&cnt[b], 1);
                const int pos = base[b] + r;
                if (pos < EDGE_CAP)
                    binned[(size_t)b * EDGE_CAP + pos] = s4.y | ((d4.y & (NODES_PER_BKT - 1)) << 17);
            }
            {
                const int b = d4.z >> NBKT_BITS;
                const int r = atomicAdd(&cnt[b], 1);
                const int pos = base[b] + r;
                if (pos < EDGE_CAP)
                    binned[(size_t)b * EDGE_CAP + pos] = s4.z | ((d4.z & (NODES_PER_BKT - 1)) << 17);
            }
            {
                const int b = d4.w >> NBKT_BITS;
                const int r = atomicAdd(&cnt[b], 1);
                const int pos = base[b] + r;
                if (pos < EDGE_CAP)
                    binned[(size_t)b * EDGE_CAP + pos] = s4.w | ((d4.w & (NODES_PER_BKT - 1)) << 17);
            }
        }
    } else {
        for (int i = beg + threadIdx.x; i < end; i += blockDim.x) {
            const int d = dst[i];
            const int b = d >> NBKT_BITS;
            const int r = atomicAdd(&cnt[b], 1);
            const int pos = base[b] + r;
            if (pos < EDGE_CAP)
                binned[(size_t)b * EDGE_CAP + pos] = src[i] | ((d & (NODES_PER_BKT - 1)) << 17);
        }
    }
}

// ---------- fused LDS sort + async-staged gather, 512 threads ----------
__global__ __launch_bounds__(512) void gather_kernel(
        const float* __restrict__ feat, const int* __restrict__ bcnt,
        const int* __restrict__ binned, float* __restrict__ out, int N) {
    __shared__ int   lsort[EDGE_CAP];              // 8 KB
    __shared__ float stage[8][BATCH * 64];         // 8 waves x 4 KB = 32 KB
    __shared__ int   lbeg[NODES_PER_BKT + 1];
    __shared__ int   lcur[NODES_PER_BKT];
    __shared__ int   lcnt[NODES_PER_BKT];
    const int b = blockIdx.x;
    const int t = threadIdx.x;
    const size_t gbeg = (size_t)b * EDGE_CAP;
    const int cnt = min(bcnt[b], EDGE_CAP);

    // ---- sort phase (r8, proven ~6us) ----
    if (t < NODES_PER_BKT) lcnt[t] = 0;
    __syncthreads();
    int p0 = -1, p1 = -1, p2 = -1, p3 = -1;
    if (t < cnt)        { p0 = binned[gbeg + t];        atomicAdd(&lcnt[(p0 >> 17) & 127], 1); }
    if (t + 512 < cnt)  { p1 = binned[gbeg + t + 512];  atomicAdd(&lcnt[(p1 >> 17) & 127], 1); }
    if (t + 1024 < cnt) { p2 = binned[gbeg + t + 1024]; atomicAdd(&lcnt[(p2 >> 17) & 127], 1); }
    if (t + 1536 < cnt) { p3 = binned[gbeg + t + 1536]; atomicAdd(&lcnt[(p3 >> 17) & 127], 1); }
    __syncthreads();
    if (t < 64) {
        const int a = lcnt[2 * t];
        const int c = lcnt[2 * t + 1];
        int s = a + c;
        for (int off = 1; off < 64; off <<= 1) {
            const int u = __shfl_up(s, off);
            if (t >= off) s += u;
        }
        const int ex = s - (a + c);
        lbeg[2 * t] = ex;         lcur[2 * t] = ex;
        lbeg[2 * t + 1] = ex + a; lcur[2 * t + 1] = ex + a;
        if (t == 63) lbeg[NODES_PER_BKT] = s;
    }
    __syncthreads();
    if (p0 >= 0) { const int r = atomicAdd(&lcur[(p0 >> 17) & 127], 1); lsort[r] = p0 & SRC_MASK; }
    if (p1 >= 0) { const int r = atomicAdd(&lcur[(p1 >> 17) & 127], 1); lsort[r] = p1 & SRC_MASK; }
    if (p2 >= 0) { const int r = atomicAdd(&lcur[(p2 >> 17) & 127], 1); lsort[r] = p2 & SRC_MASK; }
    if (p3 >= 0) { const int r = atomicAdd(&lcur[(p3 >> 17) & 127], 1); lsort[r] = p3 & SRC_MASK; }
    __syncthreads();

    // ---- gather phase: wave owns 16 nodes; per round stage 16 edge-rows
    // via 4 fire-and-forget global_load_lds, then reduce lane=column ----
    const int wave = t >> 6;
    const int lane = t & 63;
    const int n0 = wave * NPW;                 // local node base
    const int node0 = b * NODES_PER_BKT;       // global node base of bucket
    int k = lbeg[n0];
    const int kend = lbeg[n0 + NPW];

    int nloc = 0;
    // flush leading empty nodes
    while (nloc < NPW && lbeg[n0 + nloc + 1] == k) {
        const int g = node0 + n0 + nloc;
        if (g < N) out[(size_t)g * 64 + lane] = 0.f;
        ++nloc;
    }
    int nend = (nloc < NPW) ? lbeg[n0 + nloc + 1] : kend;
    float acc = 0.f;
    float* wstage = &stage[wave][0];

    while (k < kend) {
        // stage BATCH edges: instr q covers edges k+q*4 .. k+q*4+3 (clamped)
        #pragma unroll
        for (int q = 0; q < 4; ++q) {
            int e = k + q * 4 + (lane >> 4);
            e = min(e, kend - 1);
            const int s = lsort[e];
            const unsigned int* g =
                reinterpret_cast<const unsigned int*>(feat) + (size_t)s * 64 + (lane & 15) * 4;
            __builtin_amdgcn_global_load_lds(
                (gas_ptr)g, (las_ptr)(wstage + q * 256), 16, 0, 0);
        }
        asm volatile("s_waitcnt vmcnt(0)" ::: "memory");
        const int m = min(BATCH, kend - k);
        for (int j = 0; j < m; ++j, ++k) {
            acc += wstage[j * 64 + lane];
            if (k + 1 == nend) {
                const int g = node0 + n0 + nloc;
                if (g < N) out[(size_t)g * 64 + lane] = acc;
                acc = 0.f;
                ++nloc;
                while (nloc < NPW && lbeg[n0 + nloc + 1] == k + 1) {
                    const int gz = node0 + n0 + nloc;
                    if (gz < N) out[(size_t)gz * 64 + lane] = 0.f;
                    ++nloc;
                }
                nend = (nloc < NPW) ? lbeg[n0 + nloc + 1] : 0x7FFFFFFF;
            }
        }
    }
}

// ---------- last-resort fallback ----------
__global__ void atomic_fallback_kernel(const float* __restrict__ feat,
                                       const int* __restrict__ src,
                                       const int* __restrict__ dst,
                                       float* __restrict__ out, int E) {
    const int total = E * 16;
    int idx = blockIdx.x * blockDim.x + threadIdx.x;
    const int stride = gridDim.x * blockDim.x;
    for (int i = idx; i < total; i += stride) {
        const int e = i >> 4;
        const int part = i & 15;
        const float4 v = *reinterpret_cast<const float4*>(feat + (size_t)src[e] * 64 + part * 4);
        float* o = out + (size_t)dst[e] * 64 + part * 4;
        unsafeAtomicAdd(o + 0, v.x);
        unsafeAtomicAdd(o + 1, v.y);
        unsafeAtomicAdd(o + 2, v.z);
        unsafeAtomicAdd(o + 3, v.w);
    }
}

extern "C" void kernel_launch(void* const* d_in, const int* in_sizes, int n_in,
                              void* d_out, int out_size, void* d_ws, size_t ws_size,
                              hipStream_t stream) {
    const float* feat = (const float*)d_in[0];
    const int*   src  = (const int*)d_in[1];
    const int*   dst  = (const int*)d_in[2];
    float*       out  = (float*)d_out;
    const int E = in_sizes[1];
    const int N = out_size / 64;                          // 100000
    const int NB = (N + NODES_PER_BKT - 1) >> NBKT_BITS;  // 782
    const int binGrid = (E + BIN_CHUNK - 1) / BIN_CHUNK;  // 293

    const size_t need = ((size_t)NBKT_CAP + (size_t)NB * EDGE_CAP) * sizeof(int);
    const bool shape_ok = (NB <= NBKT_CAP) && (N <= SRC_MASK + 1);

    if (shape_ok && ws_size >= need) {
        int* bcnt   = (int*)d_ws;        // NBKT_CAP
        int* binned = bcnt + NBKT_CAP;   // NB * EDGE_CAP slots
        hipMemsetAsync(bcnt, 0, (size_t)NBKT_CAP * sizeof(int), stream);
        bin_direct_kernel<<<binGrid, 1024, 0, stream>>>(src, dst, bcnt, binned, E, NB);
        gather_kernel<<<NB, 512, 0, stream>>>(feat, bcnt, binned, out, N);
    } else {
        hipMemsetAsync(out, 0, (size_t)out_size * sizeof(float), stream);
        int grid = (E * 16 + 255) / 256;
        if (grid > 4096) grid = 4096;
        atomic_fallback_kernel<<<grid, 256, 0, stream>>>(feat, src, dst, out, E);
    }
}